// Round 1
// baseline (614.209 us; speedup 1.0000x reference)
//
#include <hip/hip_runtime.h>
#include <stdint.h>

#define DIM    680
#define DPAD   768      // 3 x 256 tiles, 24 x 32
#define NCH    864      // 55296 / 64 g-chunks
#define NB_Q   24
#define SPLITS 54
#define STAGES 16       // NCH / SPLITS

typedef __bf16 bf16x8 __attribute__((ext_vector_type(8)));
typedef float  f32x16 __attribute__((ext_vector_type(16)));

static __device__ __forceinline__ unsigned short f2bf(float x) {
    union { float f; unsigned u; } c; c.f = x;
    unsigned u = c.u;
    unsigned r = (u + 0x7FFFu + ((u >> 16) & 1u)) >> 16;  // RNE
    return (unsigned short)r;
}

// ---------------------------------------------------------------------------
// k1: D (55296 x 680 fp32) -> Awt bf16, scaled by sqrt(qw[b]), chunk-transposed:
//     16B slot (chunk cg, col i, kc) at uint4 index ((cg*768 + i)*8 + (kc ^ (i&7)))
//     holding g = cg*64 + kc*8 + 0..7 of column i.  Cols 680..767 zero-padded.
// ---------------------------------------------------------------------------
__global__ __launch_bounds__(256) void k1_transpose(
        const float* __restrict__ D, const float* __restrict__ qw,
        uint4* __restrict__ awt) {
    __shared__ float sq[NB_Q];
    __shared__ float tile[64][65];
    const int t  = threadIdx.x;
    const int cg = blockIdx.x;
    const int i0 = blockIdx.y * 64;
    const int g0 = cg * 64;
    if (t < NB_Q) sq[t] = sqrtf(qw[t]);
    __syncthreads();

    const int rb = t >> 4;
    const int c4 = (t & 15) * 4;
#pragma unroll
    for (int j = 0; j < 4; ++j) {
        const int r = rb + j * 16;
        const int g = g0 + r;
        const float w = sq[(g / 48) % 24];
        const int colg = i0 + c4;
        float4 v;
        if (colg + 3 < DIM) {
            v = *reinterpret_cast<const float4*>(D + (size_t)g * DIM + colg);
        } else {
            v.x = (colg + 0 < DIM) ? D[(size_t)g * DIM + colg + 0] : 0.f;
            v.y = (colg + 1 < DIM) ? D[(size_t)g * DIM + colg + 1] : 0.f;
            v.z = (colg + 2 < DIM) ? D[(size_t)g * DIM + colg + 2] : 0.f;
            v.w = (colg + 3 < DIM) ? D[(size_t)g * DIM + colg + 3] : 0.f;
        }
        tile[r][c4 + 0] = v.x * w;
        tile[r][c4 + 1] = v.y * w;
        tile[r][c4 + 2] = v.z * w;
        tile[r][c4 + 3] = v.w * w;
    }
    __syncthreads();

#pragma unroll
    for (int s = 0; s < 2; ++s) {
        const int l  = t + s * 256;
        const int c  = l >> 3;     // local col 0..63
        const int kc = l & 7;      // 16B chunk within col
        unsigned short h[8];
#pragma unroll
        for (int j = 0; j < 8; ++j) h[j] = f2bf(tile[kc * 8 + j][c]);
        uint4 o;
        o.x = (unsigned)h[0] | ((unsigned)h[1] << 16);
        o.y = (unsigned)h[2] | ((unsigned)h[3] << 16);
        o.z = (unsigned)h[4] | ((unsigned)h[5] << 16);
        o.w = (unsigned)h[6] | ((unsigned)h[7] << 16);
        const size_t slot = ((size_t)cg * DPAD + (size_t)(i0 + c)) * 8
                          + (size_t)(kc ^ (c & 7));   // i0 % 8 == 0
        awt[slot] = o;
    }
}

// ---------------------------------------------------------------------------
// k2: M(768x768 fp32, ws) += Awt^T * Awt, split-K over 54 chunks of 1024 g's.
//     grid (54 splits, 3 tj, 3 ti), 512 threads = 8 waves (4 m x 2 n),
//     wave tile 64x128, mfma_f32_32x32x16_bf16, atomicAdd epilogue.
// ---------------------------------------------------------------------------
__global__ __launch_bounds__(512) void k2_gram(const uint4* __restrict__ awt,
                                               float* __restrict__ M) {
    __shared__ uint4 smA[2048];   // 256 cols x 8 slots (swizzled), 32 KB
    __shared__ uint4 smB[2048];
    const int t     = threadIdx.x;
    const int split = blockIdx.x;
    const int tj    = blockIdx.y;
    const int ti    = blockIdx.z;
    const int wave  = t >> 6;
    const int lane  = t & 63;
    const int wm    = wave & 3;   // m: 64-row band
    const int wn    = wave >> 2;  // n: 128-col band
    const int cl    = lane & 31;
    const int half  = lane >> 5;

    f32x16 acc[2][4];
    const f32x16 zero = {};
#pragma unroll
    for (int a = 0; a < 2; ++a)
#pragma unroll
        for (int b = 0; b < 4; ++b) acc[a][b] = zero;

    uint4 ra[4], rb4[4];
    {
        const size_t bA = ((size_t)(split * STAGES) * DPAD + tj * 256) * 8;
        const size_t bB = ((size_t)(split * STAGES) * DPAD + ti * 256) * 8;
#pragma unroll
        for (int j = 0; j < 4; ++j) {
            ra[j]  = awt[bA + j * 512 + t];
            rb4[j] = awt[bB + j * 512 + t];
        }
    }

    for (int st = 0; st < STAGES; ++st) {
        __syncthreads();
#pragma unroll
        for (int j = 0; j < 4; ++j) {
            smA[j * 512 + t] = ra[j];
            smB[j * 512 + t] = rb4[j];
        }
        __syncthreads();
        if (st + 1 < STAGES) {  // prefetch next stage into registers
            const int cg = split * STAGES + st + 1;
            const size_t bA = ((size_t)cg * DPAD + tj * 256) * 8;
            const size_t bB = ((size_t)cg * DPAD + ti * 256) * 8;
#pragma unroll
            for (int j = 0; j < 4; ++j) {
                ra[j]  = awt[bA + j * 512 + t];
                rb4[j] = awt[bB + j * 512 + t];
            }
        }
        const bf16x8* pA = reinterpret_cast<const bf16x8*>(smA);
        const bf16x8* pB = reinterpret_cast<const bf16x8*>(smB);
#pragma unroll
        for (int t4 = 0; t4 < 4; ++t4) {          // K = 64 per stage, 16/mfma
            const int kc = 2 * t4 + half;
            bf16x8 af[2], bfr[4];
#pragma unroll
            for (int ms = 0; ms < 2; ++ms) {
                const int col = wm * 64 + ms * 32 + cl;
                af[ms] = pA[col * 8 + (kc ^ (col & 7))];
            }
#pragma unroll
            for (int ns = 0; ns < 4; ++ns) {
                const int col = wn * 128 + ns * 32 + cl;
                bfr[ns] = pB[col * 8 + (kc ^ (col & 7))];
            }
#pragma unroll
            for (int ms = 0; ms < 2; ++ms)
#pragma unroll
                for (int ns = 0; ns < 4; ++ns)
                    acc[ms][ns] = __builtin_amdgcn_mfma_f32_32x32x16_bf16(
                        af[ms], bfr[ns], acc[ms][ns], 0, 0, 0);
        }
    }

#pragma unroll
    for (int ms = 0; ms < 2; ++ms)
#pragma unroll
        for (int ns = 0; ns < 4; ++ns) {
            const int coln = ti * 256 + wn * 128 + ns * 32 + cl;
            const int rowb = tj * 256 + wm * 64 + ms * 32 + 4 * half;
#pragma unroll
            for (int r = 0; r < 16; ++r) {
                const int row = rowb + (r & 3) + 8 * (r >> 2);  // C/D layout (m101)
                atomicAdd(&M[(size_t)row * DPAD + coln], acc[ms][ns][r]);
            }
        }
}

// ---------------------------------------------------------------------------
// k3: out(1024x680) = F(1024x680) @ M(768-stride, rows/cols >=680 are zero).
//     fp32 tiled GEMM, 64x64 tile / block, 256 threads, 4x4 per thread.
// ---------------------------------------------------------------------------
__global__ __launch_bounds__(256) void k3_out(const float* __restrict__ F,
                                              const float* __restrict__ M,
                                              float* __restrict__ out) {
    __shared__ float Ft[32][68];   // [k][n]
    __shared__ float Ms[32][68];   // [k][i]
    const int t  = threadIdx.x;
    const int tx = t & 15;
    const int ty = t >> 4;
    const int n0 = blockIdx.x * 64;
    const int i0 = blockIdx.y * 64;
    float acc[4][4] = {};

    for (int k0 = 0; k0 < DIM; k0 += 32) {
        __syncthreads();
        {
            const int kk = t & 31;
            const int nb = t >> 5;
#pragma unroll
            for (int rr = 0; rr < 8; ++rr) {
                const int n = nb * 8 + rr;
                const int k = k0 + kk;
                Ft[kk][n] = (k < DIM) ? F[(size_t)(n0 + n) * DIM + k] : 0.f;
            }
        }
        {
            const int i  = t & 63;
            const int kb = t >> 6;
#pragma unroll
            for (int rr = 0; rr < 8; ++rr) {
                const int kk = kb * 8 + rr;
                const int k = k0 + kk;
                Ms[kk][i] = (k < DIM) ? M[(size_t)k * DPAD + i0 + i] : 0.f;
            }
        }
        __syncthreads();
#pragma unroll
        for (int kk = 0; kk < 32; ++kk) {
            const float4 a = *reinterpret_cast<const float4*>(&Ft[kk][ty * 4]);
            const float4 b = *reinterpret_cast<const float4*>(&Ms[kk][tx * 4]);
            acc[0][0] += a.x * b.x; acc[0][1] += a.x * b.y;
            acc[0][2] += a.x * b.z; acc[0][3] += a.x * b.w;
            acc[1][0] += a.y * b.x; acc[1][1] += a.y * b.y;
            acc[1][2] += a.y * b.z; acc[1][3] += a.y * b.w;
            acc[2][0] += a.z * b.x; acc[2][1] += a.z * b.y;
            acc[2][2] += a.z * b.z; acc[2][3] += a.z * b.w;
            acc[3][0] += a.w * b.x; acc[3][1] += a.w * b.y;
            acc[3][2] += a.w * b.z; acc[3][3] += a.w * b.w;
        }
    }

#pragma unroll
    for (int r = 0; r < 4; ++r) {
        const int n = n0 + ty * 4 + r;
#pragma unroll
        for (int c = 0; c < 4; ++c) {
            const int i = i0 + tx * 4 + c;
            if (i < DIM) out[(size_t)n * DIM + i] = acc[r][c];
        }
    }
}

extern "C" void kernel_launch(void* const* d_in, const int* in_sizes, int n_in,
                              void* d_out, int out_size, void* d_ws, size_t ws_size,
                              hipStream_t stream) {
    const float* F  = (const float*)d_in[0];   // (1024, 680)
    const float* D  = (const float*)d_in[1];   // (48, 24, 48, 680)
    const float* qw = (const float*)d_in[2];   // (24,)
    float* out = (float*)d_out;
    char*  ws  = (char*)d_ws;

    uint4* awt = (uint4*)ws;                                    // 81.0 MiB bf16
    const size_t awt_bytes = (size_t)NCH * DPAD * 64 * 2;       // 84,934,656
    float* M = (float*)(ws + awt_bytes);                        // 2.25 MiB fp32

    k1_transpose<<<dim3(NCH, DPAD / 64), 256, 0, stream>>>(D, qw, awt);
    hipMemsetAsync(M, 0, (size_t)DPAD * DPAD * sizeof(float), stream);
    k2_gram<<<dim3(SPLITS, 3, 3), 512, 0, stream>>>(awt, M);
    k3_out<<<dim3(16, 11), 256, 0, stream>>>(F, M, out);
}

// Round 2
// 499.318 us; speedup vs baseline: 1.2301x; 1.2301x over previous
//
#include <hip/hip_runtime.h>
#include <stdint.h>

#define DIM    680
#define DPAD   768      // 3 x 256 tiles
#define NCH    864      // 55296 / 64 g-chunks
#define NB_Q   24
#define SPLITS 72
#define STAGES 12       // NCH / SPLITS
#define NTILE  6        // upper-triangle 256x256 tiles of 3x3

typedef __bf16 bf16x8 __attribute__((ext_vector_type(8)));
typedef float  f32x16 __attribute__((ext_vector_type(16)));

__constant__ int c_tj[NTILE] = {0, 0, 0, 1, 1, 2};
__constant__ int c_ti[NTILE] = {0, 1, 2, 1, 2, 2};

static __device__ __forceinline__ unsigned short f2bf(float x) {
    union { float f; unsigned u; } c; c.f = x;
    unsigned u = c.u;
    unsigned r = (u + 0x7FFFu + ((u >> 16) & 1u)) >> 16;  // RNE
    return (unsigned short)r;
}

static __device__ __forceinline__ float bf2f(unsigned short h) {
    union { unsigned u; float f; } c; c.u = ((unsigned)h) << 16;
    return c.f;
}

// ---------------------------------------------------------------------------
// k1: D (55296 x 680 fp32) -> Awt bf16, scaled by sqrt(qw[b]), chunk-transposed:
//     16B slot (chunk cg, col i, kc) at uint4 index ((cg*768 + i)*8 + (kc ^ (i&7)))
//     holding g = cg*64 + kc*8 + 0..7 of column i.  Cols 680..767 zero-padded.
// ---------------------------------------------------------------------------
__global__ __launch_bounds__(256) void k1_transpose(
        const float* __restrict__ D, const float* __restrict__ qw,
        uint4* __restrict__ awt) {
    __shared__ float sq[NB_Q];
    __shared__ float tile[64][65];
    const int t  = threadIdx.x;
    const int cg = blockIdx.x;
    const int i0 = blockIdx.y * 64;
    const int g0 = cg * 64;
    if (t < NB_Q) sq[t] = sqrtf(qw[t]);
    __syncthreads();

    const int rb = t >> 4;
    const int c4 = (t & 15) * 4;
#pragma unroll
    for (int j = 0; j < 4; ++j) {
        const int r = rb + j * 16;
        const int g = g0 + r;
        const float w = sq[(g / 48) % 24];
        const int colg = i0 + c4;
        float4 v;
        if (colg + 3 < DIM) {
            v = *reinterpret_cast<const float4*>(D + (size_t)g * DIM + colg);
        } else {
            v.x = (colg + 0 < DIM) ? D[(size_t)g * DIM + colg + 0] : 0.f;
            v.y = (colg + 1 < DIM) ? D[(size_t)g * DIM + colg + 1] : 0.f;
            v.z = (colg + 2 < DIM) ? D[(size_t)g * DIM + colg + 2] : 0.f;
            v.w = (colg + 3 < DIM) ? D[(size_t)g * DIM + colg + 3] : 0.f;
        }
        tile[r][c4 + 0] = v.x * w;
        tile[r][c4 + 1] = v.y * w;
        tile[r][c4 + 2] = v.z * w;
        tile[r][c4 + 3] = v.w * w;
    }
    __syncthreads();

#pragma unroll
    for (int s = 0; s < 2; ++s) {
        const int l  = t + s * 256;
        const int c  = l >> 3;     // local col 0..63
        const int kc = l & 7;      // 16B chunk within col
        unsigned short h[8];
#pragma unroll
        for (int j = 0; j < 8; ++j) h[j] = f2bf(tile[kc * 8 + j][c]);
        uint4 o;
        o.x = (unsigned)h[0] | ((unsigned)h[1] << 16);
        o.y = (unsigned)h[2] | ((unsigned)h[3] << 16);
        o.z = (unsigned)h[4] | ((unsigned)h[5] << 16);
        o.w = (unsigned)h[6] | ((unsigned)h[7] << 16);
        const size_t slot = ((size_t)cg * DPAD + (size_t)(i0 + c)) * 8
                          + (size_t)(kc ^ (c & 7));   // i0 % 8 == 0
        awt[slot] = o;
    }
}

// ---------------------------------------------------------------------------
// k2: partial[split][tile] (256x256 bf16) = sum over this split's 12 chunks of
//     A_band(tj)^T * A_band(ti), upper-triangle tiles only (M symmetric).
//     grid (72 splits, 6 tiles), 512 threads = 8 waves (4 m x 2 n),
//     wave tile 64x128, mfma_f32_32x32x16_bf16, streaming bf16 store epilogue.
// ---------------------------------------------------------------------------
__global__ __launch_bounds__(512) void k2_gram(const uint4* __restrict__ awt,
                                               unsigned short* __restrict__ parts) {
    __shared__ uint4 smA[2048];   // 256 cols x 8 slots (swizzled), 32 KB
    __shared__ uint4 smB[2048];
    const int t     = threadIdx.x;
    const int split = blockIdx.x;
    const int t6    = blockIdx.y;
    const int tj    = c_tj[t6];   // row band of M
    const int ti    = c_ti[t6];   // col band of M
    const int wave  = t >> 6;
    const int lane  = t & 63;
    const int wm    = wave & 3;   // m: 64-row band
    const int wn    = wave >> 2;  // n: 128-col band
    const int cl    = lane & 31;
    const int half  = lane >> 5;

    f32x16 acc[2][4];
    const f32x16 zero = {};
#pragma unroll
    for (int a = 0; a < 2; ++a)
#pragma unroll
        for (int b = 0; b < 4; ++b) acc[a][b] = zero;

    uint4 ra[4], rb4[4];
    {
        const size_t bA = ((size_t)(split * STAGES) * DPAD + tj * 256) * 8;
        const size_t bB = ((size_t)(split * STAGES) * DPAD + ti * 256) * 8;
#pragma unroll
        for (int j = 0; j < 4; ++j) {
            ra[j]  = awt[bA + j * 512 + t];
            rb4[j] = awt[bB + j * 512 + t];
        }
    }

    for (int st = 0; st < STAGES; ++st) {
        __syncthreads();
#pragma unroll
        for (int j = 0; j < 4; ++j) {
            smA[j * 512 + t] = ra[j];
            smB[j * 512 + t] = rb4[j];
        }
        __syncthreads();
        if (st + 1 < STAGES) {  // prefetch next stage into registers
            const int cg = split * STAGES + st + 1;
            const size_t bA = ((size_t)cg * DPAD + tj * 256) * 8;
            const size_t bB = ((size_t)cg * DPAD + ti * 256) * 8;
#pragma unroll
            for (int j = 0; j < 4; ++j) {
                ra[j]  = awt[bA + j * 512 + t];
                rb4[j] = awt[bB + j * 512 + t];
            }
        }
        const bf16x8* pA = reinterpret_cast<const bf16x8*>(smA);
        const bf16x8* pB = reinterpret_cast<const bf16x8*>(smB);
#pragma unroll
        for (int t4 = 0; t4 < 4; ++t4) {          // K = 64 per stage, 16/mfma
            const int kc = 2 * t4 + half;
            bf16x8 af[2], bfr[4];
#pragma unroll
            for (int ms = 0; ms < 2; ++ms) {
                const int col = wm * 64 + ms * 32 + cl;
                af[ms] = pA[col * 8 + (kc ^ (col & 7))];
            }
#pragma unroll
            for (int ns = 0; ns < 4; ++ns) {
                const int col = wn * 128 + ns * 32 + cl;
                bfr[ns] = pB[col * 8 + (kc ^ (col & 7))];
            }
#pragma unroll
            for (int ms = 0; ms < 2; ++ms)
#pragma unroll
                for (int ns = 0; ns < 4; ++ns)
                    acc[ms][ns] = __builtin_amdgcn_mfma_f32_32x32x16_bf16(
                        af[ms], bfr[ns], acc[ms][ns], 0, 0, 0);
        }
    }

    // streaming bf16 partial store (no atomics)
    unsigned short* pt = parts + (size_t)(split * NTILE + t6) * 65536;
#pragma unroll
    for (int ms = 0; ms < 2; ++ms)
#pragma unroll
        for (int ns = 0; ns < 4; ++ns) {
            const int colt = wn * 128 + ns * 32 + cl;
            const int rowb = wm * 64 + ms * 32 + 4 * half;
#pragma unroll
            for (int r = 0; r < 16; ++r) {
                const int rowt = rowb + (r & 3) + 8 * (r >> 2);  // C/D layout (m101)
                pt[rowt * 256 + colt] = f2bf(acc[ms][ns][r]);
            }
        }
}

// ---------------------------------------------------------------------------
// k2r: M[768x768 fp32] = sum over 72 split-partials per tile, + mirror.
//     grid (64, 6), 256 threads, float4 per thread.
// ---------------------------------------------------------------------------
__global__ __launch_bounds__(256) void k2_reduce(
        const unsigned short* __restrict__ parts, float* __restrict__ M) {
    const int t6 = blockIdx.y;
    const int tj = c_tj[t6];
    const int ti = c_ti[t6];
    const int idx = blockIdx.x * 1024 + threadIdx.x * 4;
    float4 s = {0.f, 0.f, 0.f, 0.f};
#pragma unroll 8
    for (int sp = 0; sp < SPLITS; ++sp) {
        const ushort4 u = *reinterpret_cast<const ushort4*>(
            parts + (size_t)(sp * NTILE + t6) * 65536 + idx);
        s.x += bf2f(u.x);
        s.y += bf2f(u.y);
        s.z += bf2f(u.z);
        s.w += bf2f(u.w);
    }
    const int rowt = idx >> 8;
    const int colt = idx & 255;
    const int r = tj * 256 + rowt;
    const int c = ti * 256 + colt;
    *reinterpret_cast<float4*>(M + (size_t)r * DPAD + c) = s;
    if (ti != tj) {
        M[(size_t)(c + 0) * DPAD + r] = s.x;
        M[(size_t)(c + 1) * DPAD + r] = s.y;
        M[(size_t)(c + 2) * DPAD + r] = s.z;
        M[(size_t)(c + 3) * DPAD + r] = s.w;
    }
}

// ---------------------------------------------------------------------------
// k3: out(1024x680) = F(1024x680) @ M(768-stride).
//     fp32 tiled GEMM, 64x64 tile / block, 256 threads, 4x4 per thread.
// ---------------------------------------------------------------------------
__global__ __launch_bounds__(256) void k3_out(const float* __restrict__ F,
                                              const float* __restrict__ M,
                                              float* __restrict__ out) {
    __shared__ float Ft[32][68];   // [k][n]
    __shared__ float Ms[32][68];   // [k][i]
    const int t  = threadIdx.x;
    const int tx = t & 15;
    const int ty = t >> 4;
    const int n0 = blockIdx.x * 64;
    const int i0 = blockIdx.y * 64;
    float acc[4][4] = {};

    for (int k0 = 0; k0 < DIM; k0 += 32) {
        __syncthreads();
        {
            const int kk = t & 31;
            const int nb = t >> 5;
#pragma unroll
            for (int rr = 0; rr < 8; ++rr) {
                const int n = nb * 8 + rr;
                const int k = k0 + kk;
                Ft[kk][n] = (k < DIM) ? F[(size_t)(n0 + n) * DIM + k] : 0.f;
            }
        }
        {
            const int i  = t & 63;
            const int kb = t >> 6;
#pragma unroll
            for (int rr = 0; rr < 8; ++rr) {
                const int kk = kb * 8 + rr;
                const int k = k0 + kk;
                Ms[kk][i] = (k < DIM) ? M[(size_t)k * DPAD + i0 + i] : 0.f;
            }
        }
        __syncthreads();
#pragma unroll
        for (int kk = 0; kk < 32; ++kk) {
            const float4 a = *reinterpret_cast<const float4*>(&Ft[kk][ty * 4]);
            const float4 b = *reinterpret_cast<const float4*>(&Ms[kk][tx * 4]);
            acc[0][0] += a.x * b.x; acc[0][1] += a.x * b.y;
            acc[0][2] += a.x * b.z; acc[0][3] += a.x * b.w;
            acc[1][0] += a.y * b.x; acc[1][1] += a.y * b.y;
            acc[1][2] += a.y * b.z; acc[1][3] += a.y * b.w;
            acc[2][0] += a.z * b.x; acc[2][1] += a.z * b.y;
            acc[2][2] += a.z * b.z; acc[2][3] += a.z * b.w;
            acc[3][0] += a.w * b.x; acc[3][1] += a.w * b.y;
            acc[3][2] += a.w * b.z; acc[3][3] += a.w * b.w;
        }
    }

#pragma unroll
    for (int r = 0; r < 4; ++r) {
        const int n = n0 + ty * 4 + r;
#pragma unroll
        for (int c = 0; c < 4; ++c) {
            const int i = i0 + tx * 4 + c;
            if (i < DIM) out[(size_t)n * DIM + i] = acc[r][c];
        }
    }
}

extern "C" void kernel_launch(void* const* d_in, const int* in_sizes, int n_in,
                              void* d_out, int out_size, void* d_ws, size_t ws_size,
                              hipStream_t stream) {
    const float* F  = (const float*)d_in[0];   // (1024, 680)
    const float* D  = (const float*)d_in[1];   // (48, 24, 48, 680)
    const float* qw = (const float*)d_in[2];   // (24,)
    float* out = (float*)d_out;
    char*  ws  = (char*)d_ws;

    uint4* awt = (uint4*)ws;                                    // 81.0 MiB bf16
    const size_t awt_bytes = (size_t)NCH * DPAD * 64 * 2;       // 84,934,656
    unsigned short* parts = (unsigned short*)(ws + awt_bytes);  // 54.0 MiB bf16
    const size_t parts_bytes = (size_t)SPLITS * NTILE * 65536 * 2;  // 56,623,104
    float* M = (float*)(ws + awt_bytes + parts_bytes);          // 2.25 MiB fp32

    k1_transpose<<<dim3(NCH, DPAD / 64), 256, 0, stream>>>(D, qw, awt);
    k2_gram<<<dim3(SPLITS, NTILE), 512, 0, stream>>>(awt, parts);
    k2_reduce<<<dim3(64, NTILE), 256, 0, stream>>>(parts, M);
    k3_out<<<dim3(16, 11), 256, 0, stream>>>(F, M, out);
}